// Round 12
// baseline (229.344 us; speedup 1.0000x reference)
//
#include <hip/hip_runtime.h>
#include <stdint.h>
#include <math.h>

// Problem constants
constexpr int T_ = 4;
constexpr int B_ = 8;
constexpr int C_ = 256;
constexpr int N_ = 256;          // H*W
constexpr int TN_ = 1024;        // T*N
constexpr int NH_ = 8;           // heads
constexpr int O3_ = 768;         // 3*C
constexpr int BIAS_ROWS_ = 6727; // 7*31*31

__device__ __constant__ int TI_OF[10] = {0,1,1,2,2,2,3,3,3,3};
__device__ __constant__ int TJ_OF[10] = {0,0,1,0,1,2,0,1,2,3};

__device__ __forceinline__ float quant1f(float m) {
    return rintf(fminf(fmaxf(m, 0.0f), 1.0f));
}

// ---------------------------------------------------------------------------
// K1: qkv = BN(w_qkv @ xf)   out[b][o][l]
// 128(M) x 128(N) tile, 8x8 microtile (16 FMA per ds_read_b128 vs 10.7 in
// R11's 8x4 -- both GEMMs are LDS-instruction-bound at ~12cyc/b128).
// Batch-merged grid 64(l-tiles) x 6(o-tiles) = 384 blocks. K-chunk 32.
// Reads: rows {ty*4,64+ty*4} broadcast; cols {tx*4,64+tx*4} 16B stride (the
// verified conflict-free pattern; R7's 32B stride was the 4-way trap).
// Ascending-k accumulation (bit-identical).
// ---------------------------------------------------------------------------
__global__ __launch_bounds__(256) void k1_qkv_gemm(
    const float* __restrict__ x, const float* __restrict__ w,
    const float* __restrict__ gamma, const float* __restrict__ beta,
    const float* __restrict__ mean, const float* __restrict__ var,
    float* __restrict__ out)
{
    __shared__ float At[32][132];  // [k][m], m=128 (+4 pad)
    __shared__ float Bt[32][132];  // [k][n], n=128 (+4 pad)
    const int lTile = blockIdx.x;          // 0..63 over b*8 + l/128
    const int oBase = blockIdx.y * 128;    // 0..5
    const int b = lTile >> 3;
    const int lBase = (lTile & 7) * 128;
    const int tid = threadIdx.x;
    const int ty = tid >> 4, tx = tid & 15;
    const float* xb = x + (size_t)b * C_ * TN_;

    float acc[8][8];
#pragma unroll
    for (int i = 0; i < 8; ++i)
#pragma unroll
        for (int j = 0; j < 8; ++j) acc[i][j] = 0.0f;

    // A loader: 128 rows x 32 k as float2, 8/thread
    const int a_row0 = tid >> 4, a_k2 = (tid & 15) * 2;
    // B loader: 32 k x 128 cols as float4, 4/thread
    const int b_kk0 = tid >> 5, b_c4 = (tid & 31) * 4;

    for (int kc = 0; kc < 8; ++kc) {
        const int k0 = kc * 32;
#pragma unroll
        for (int r = 0; r < 8; ++r) {
            const int row = a_row0 + 16 * r;
            const float2 v = *(const float2*)&w[(size_t)(oBase + row) * C_ + k0 + a_k2];
            At[a_k2][row] = v.x;
            At[a_k2 + 1][row] = v.y;
        }
#pragma unroll
        for (int r = 0; r < 4; ++r) {
            const int kk = b_kk0 + 8 * r;
            const float4 v = *(const float4*)&xb[(size_t)(k0 + kk) * TN_ + lBase + b_c4];
            *(float4*)&Bt[kk][b_c4] = v;
        }
        __syncthreads();
#pragma unroll
        for (int cc = 0; cc < 32; ++cc) {
            float a[8], bb[8];
            *(float4*)&a[0] = *(const float4*)&At[cc][ty * 4];
            *(float4*)&a[4] = *(const float4*)&At[cc][64 + ty * 4];
            *(float4*)&bb[0] = *(const float4*)&Bt[cc][tx * 4];
            *(float4*)&bb[4] = *(const float4*)&Bt[cc][64 + tx * 4];
#pragma unroll
            for (int i = 0; i < 8; ++i)
#pragma unroll
                for (int j = 0; j < 8; ++j) acc[i][j] += a[i] * bb[j];
        }
        __syncthreads();
    }

#pragma unroll
    for (int i = 0; i < 8; ++i) {
        const int o = oBase + (i >> 2) * 64 + ty * 4 + (i & 3);
        const float inv = 1.0f / sqrtf(var[o] + 1e-5f);
        const float g = gamma[o] * inv;
        const float mn = mean[o], bt = beta[o];
        float4 s0, s1;
        s0.x = (acc[i][0] - mn) * g + bt;
        s0.y = (acc[i][1] - mn) * g + bt;
        s0.z = (acc[i][2] - mn) * g + bt;
        s0.w = (acc[i][3] - mn) * g + bt;
        s1.x = (acc[i][4] - mn) * g + bt;
        s1.y = (acc[i][5] - mn) * g + bt;
        s1.z = (acc[i][6] - mn) * g + bt;
        s1.w = (acc[i][7] - mn) * g + bt;
        float* dst = &out[((size_t)b * O3_ + o) * TN_ + lBase];
        *(float4*)&dst[tx * 4] = s0;
        *(float4*)&dst[64 + tx * 4] = s1;
    }
}

// ---------------------------------------------------------------------------
// K2: LIF over t, pack spikes. d-quarter split (blockIdx.z 0..3), uint8
// stores; per-d recurrences independent. 768 blocks.
// ---------------------------------------------------------------------------
__global__ __launch_bounds__(256) void k2_lif_pack(
    const float* __restrict__ qkv,
    uint32_t* __restrict__ qb, uint32_t* __restrict__ kb, uint32_t* __restrict__ vb)
{
    const int n = threadIdx.x;
    const int g = blockIdx.x;
    const int b = blockIdx.y;
    const int dq = blockIdx.z;          // d = dq*8 .. dq*8+7
    const int which = g >> 3, h = g & 7;
    uint32_t* dstw = (which == 0) ? qb : (which == 1) ? kb : vb;
    uint8_t* dst = (uint8_t*)dstw;
    const float* src = qkv + ((size_t)b * O3_ + g * 32 + dq * 8) * TN_;

    float memv[8];
#pragma unroll
    for (int d = 0; d < 8; ++d) memv[d] = 0.0f;
    uint32_t prev = 0;

    for (int t = 0; t < T_; ++t) {
        uint32_t bits = 0;
#pragma unroll
        for (int d = 0; d < 8; ++d) {
            const float xv = src[(size_t)d * TN_ + t * N_ + n];
            const float m = (memv[d] - 0.5f * (float)((prev >> d) & 1u)) * 0.25f + xv;
            memv[d] = m;
            const float s = quant1f(m);
            bits |= ((uint32_t)s) << d;
        }
        prev = bits;
        dst[4 * (((size_t)b * NH_ + h) * TN_ + t * N_ + n) + dq] = (uint8_t)bits;
    }
}

// ---------------------------------------------------------------------------
// K3tgp: per-(t,bh) ballot bit-transpose + partial Gram (int). 256 blocks
// (4x the parallelism of the fused R11 version, 1/4 the serial ballots).
// ---------------------------------------------------------------------------
__global__ __launch_bounds__(256) void k3_tgp(
    const uint32_t* __restrict__ kb, const uint32_t* __restrict__ vb,
    int* __restrict__ Pt)
{
    __shared__ uint64_t ks[32][4];
    __shared__ uint64_t vs[32][4];
    const int t = blockIdx.x;
    const int bh = blockIdx.y;
    const int tid = threadIdx.x;
    const int q = tid >> 6, lane = tid & 63;
    const int j = t * N_ + q * 64 + lane;

    const uint32_t kw = kb[(size_t)bh * TN_ + j];
    const uint32_t vw = vb[(size_t)bh * TN_ + j];
#pragma unroll
    for (int d = 0; d < 32; ++d) {
        const uint64_t mk = __ballot((kw >> d) & 1u);
        const uint64_t mv = __ballot((vw >> d) & 1u);
        if (lane == 0) { ks[d][q] = mk; vs[d][q] = mv; }
    }
    __syncthreads();

    const int d = tid & 31;
#pragma unroll
    for (int s = 0; s < 4; ++s) {
        const int d2 = (tid >> 5) + 8 * s;
        int p = 0;
#pragma unroll
        for (int w = 0; w < 4; ++w) p += __popcll(ks[d2][w] & vs[d][w]);
        Pt[(size_t)(bh * 4 + t) * 1024 + d2 * 32 + d] = p;
    }
}

// ---------------------------------------------------------------------------
// K3cum: cumulative sum of partial Grams over t -> Gf (float).
// ---------------------------------------------------------------------------
__global__ __launch_bounds__(256) void k3_cum(
    const int* __restrict__ Pt, float* __restrict__ Gf)
{
    const int bh = blockIdx.x;
    const int tid = threadIdx.x;
#pragma unroll
    for (int r = 0; r < 4; ++r) {
        const int idx = tid + 256 * r;
        int cum = 0;
#pragma unroll
        for (int t = 0; t < T_; ++t) {
            cum += Pt[(size_t)(bh * 4 + t) * 1024 + idx];
            Gf[(size_t)(bh * 4 + t) * 1024 + idx] = (float)cum;
        }
    }
}

// ---------------------------------------------------------------------------
// K3gemm: balanced split-K bias GEMM, 128(i) x 128(n) tile, 8x8 microtile
// (same LDS-instruction argument as k1). K=256 (one tj), K-chunk 32.
// Grid (2 nT, 2 iT, 80) = 320 blocks. Ascending-j order (bit-identical).
// ---------------------------------------------------------------------------
__global__ __launch_bounds__(256) void k3_bias_gemm(
    const uint32_t* __restrict__ vb, const float* __restrict__ bias_table,
    float* __restrict__ p0, float* __restrict__ p1,
    float* __restrict__ p2, float* __restrict__ p3)
{
    __shared__ float sbl[720];
    __shared__ float At[32][132];  // [j-in-chunk][i-local 0..127]
    __shared__ float Bt[32][132];  // [j-in-chunk][n-local 0..127]

    const int z = blockIdx.z;
    const int h = z / 10;
    const int p = z % 10;
    const int ti = TI_OF[p], tj = TJ_OF[p];
    const int dt = ti - tj;
    const int iT = blockIdx.y;           // 0..1 (128 rows each)
    const int nBase = blockIdx.x * 128;  // 0 or 128
    const int tid = threadIdx.x;

    // stage bias window; window-local idx in [0, 716)
    const int base = 3363 + 961 * dt + 248 * iT - 480;
    for (int s = tid; s < 720; s += 256) {
        const int gidx = base + s;
        sbl[s] = (gidx >= 0 && gidx < BIAS_ROWS_) ? bias_table[(size_t)gidx * NH_ + h] : 0.0f;
    }

    const int ty = tid >> 4, tx = tid & 15;

    // A-staging: cc = tx + 16*r1, row-groups il = g*64 + ty*4 (g=0,1)
    // window idx = 31*(il>>4) + (il&15) + 480 - 31*(2kc+r1) - tx
    int sRow[2];
#pragma unroll
    for (int g = 0; g < 2; ++g) {
        const int il = g * 64 + ty * 4;
        sRow[g] = 31 * (il >> 4) + (il & 15) + 480 - tx;
    }

    // B-staging: rows kk = ty + 16r, cols tx*8..+7 (store pattern as R11)
    const int n8 = tx * 8;
    const int nS = nBase + n8;
    const int bS = nS >> 5, d0S = nS & 31;
    const uint32_t* vbw = vb + ((size_t)bS * NH_ + h) * TN_ + tj * 256 + ty;

    // compute-column mapping (16B-stride reads)
    const int nA = nBase + tx * 4;
    const int nB = nBase + 64 + tx * 4;
    const int bA = nA >> 5, dA = nA & 31;
    const int bB = nB >> 5, dB = nB & 31;

    float acc[8][8];
#pragma unroll
    for (int i = 0; i < 8; ++i)
#pragma unroll
        for (int j = 0; j < 8; ++j) acc[i][j] = 0.0f;

    __syncthreads();  // sbl ready

    for (int kc = 0; kc < 8; ++kc) {
#pragma unroll
        for (int r1 = 0; r1 < 2; ++r1) {
            const int shift = 31 * (kc * 2 + r1);
#pragma unroll
            for (int g = 0; g < 2; ++g) {
                const int s0 = sRow[g] - shift;
                float4 av;
                av.x = sbl[s0];
                av.y = sbl[s0 + 1];
                av.z = sbl[s0 + 2];
                av.w = sbl[s0 + 3];
                *(float4*)&At[tx + 16 * r1][g * 64 + ty * 4] = av;
            }
        }
#pragma unroll
        for (int r = 0; r < 2; ++r) {
            const uint32_t wd = vbw[kc * 32 + 16 * r];
            float4 b0, b1;
            b0.x = (float)((wd >> d0S) & 1u);
            b0.y = (float)((wd >> (d0S + 1)) & 1u);
            b0.z = (float)((wd >> (d0S + 2)) & 1u);
            b0.w = (float)((wd >> (d0S + 3)) & 1u);
            b1.x = (float)((wd >> (d0S + 4)) & 1u);
            b1.y = (float)((wd >> (d0S + 5)) & 1u);
            b1.z = (float)((wd >> (d0S + 6)) & 1u);
            b1.w = (float)((wd >> (d0S + 7)) & 1u);
            *(float4*)&Bt[ty + 16 * r][n8] = b0;
            *(float4*)&Bt[ty + 16 * r][n8 + 4] = b1;
        }
        __syncthreads();
#pragma unroll
        for (int cc = 0; cc < 32; ++cc) {
            float a[8], bb[8];
            *(float4*)&a[0] = *(const float4*)&At[cc][ty * 4];
            *(float4*)&a[4] = *(const float4*)&At[cc][64 + ty * 4];
            *(float4*)&bb[0] = *(const float4*)&Bt[cc][tx * 4];
            *(float4*)&bb[4] = *(const float4*)&Bt[cc][64 + tx * 4];
#pragma unroll
            for (int i = 0; i < 8; ++i)
#pragma unroll
                for (int j = 0; j < 8; ++j) acc[i][j] += a[i] * bb[j];
        }
        __syncthreads();
    }

    float* plane = (tj == 0) ? p0 : (tj == 1) ? p1 : (tj == 2) ? p2 : p3;
    const int nrows = (4 - tj) * 256;
    const int cA = h * 32 + dA;
    const int cB = h * 32 + dB;
#pragma unroll
    for (int i = 0; i < 8; ++i) {
        const int rowL = dt * 256 + iT * 128 + (i >> 2) * 64 + ty * 4 + (i & 3);
        float4 s0, s1;
        s0.x = acc[i][0]; s0.y = acc[i][1]; s0.z = acc[i][2]; s0.w = acc[i][3];
        s1.x = acc[i][4]; s1.y = acc[i][5]; s1.z = acc[i][6]; s1.w = acc[i][7];
        *(float4*)&plane[((size_t)bA * nrows + rowL) * 256 + cA] = s0;
        *(float4*)&plane[((size_t)bB * nrows + rowL) * 256 + cB] = s1;
    }
}

// ---------------------------------------------------------------------------
// K4: fused S1 + bias partials + LIF2 -> bit-packed spikes.
// ---------------------------------------------------------------------------
__global__ __launch_bounds__(256) void k4_lif2(
    const uint32_t* __restrict__ qb, const float* __restrict__ Gf,
    const float* __restrict__ p0, const float* __restrict__ p1,
    const float* __restrict__ p2, const float* __restrict__ p3,
    uint32_t* __restrict__ s2c)
{
    const int c = threadIdx.x;
    const int n = blockIdx.x;
    const int b = blockIdx.y;
    const int lane = c & 63;
    const int h = c >> 5, d = c & 31;
    const int bh = b * NH_ + h;
    const uint32_t* qbh = qb + (size_t)bh * TN_;

    float memv = 0.0f, spk = 0.0f;
    for (int t = 0; t < T_; ++t) {
        const int l = t * N_ + n;
        const uint32_t q = qbh[l];
        const float* g = Gf + (size_t)(bh * 4 + t) * 1024 + d;
        float v = 0.0f;
#pragma unroll
        for (int d2 = 0; d2 < 32; ++d2)
            v += ((q >> d2) & 1u) ? g[d2 * 32] : 0.0f;
        v += p0[((size_t)b * 1024 + l) * 256 + c];
        if (t >= 1) v += p1[((size_t)b * 768 + (l - 256)) * 256 + c];
        if (t >= 2) v += p2[((size_t)b * 512 + (l - 512)) * 256 + c];
        if (t >= 3) v += p3[((size_t)b * 256 + (l - 768)) * 256 + c];
        const float m = (memv - 0.5f * spk) * 0.25f + 0.125f * v;
        memv = m;
        const float s = quant1f(m);
        spk = s;
        const uint64_t mask = __ballot(s != 0.0f);
        if (lane == 0)
            s2c[((size_t)b * TN_ + l) * 8 + (c >> 5)] = (uint32_t)mask;
        else if (lane == 32)
            s2c[((size_t)b * TN_ + l) * 8 + (c >> 5)] = (uint32_t)(mask >> 32);
    }
}

// ---------------------------------------------------------------------------
// K5: fused proj GEMM + bias + BN + final LIF -> writes d_out directly.
// ---------------------------------------------------------------------------
__global__ __launch_bounds__(256) void k5_proj_lif(
    const uint32_t* __restrict__ s2c, const float* __restrict__ w,
    const float* __restrict__ bp,
    const float* __restrict__ gamma, const float* __restrict__ beta,
    const float* __restrict__ mean, const float* __restrict__ var,
    float* __restrict__ out)
{
    __shared__ float At[128][36];    // [k-local][row], 32 rows (+4 pad)
    __shared__ uint32_t Sw[128 * 9]; // [l'][8 words] padded to 9
    const int nBase = blockIdx.x * 32;
    const int oBase = blockIdx.y * 32;
    const int b = blockIdx.z;
    const int tid = threadIdx.x;
    const int tx = tid & 31;   // n = nBase + tx
    const int ty = tid >> 5;   // rows ty*4..+3

#pragma unroll
    for (int j = 0; j < 4; ++j) {
        const int fidx = tid * 4 + j;
        const int lp = fidx >> 3, wsel = fidx & 7;
        const int t = lp >> 5, nn = lp & 31;
        Sw[lp * 9 + wsel] = s2c[((size_t)b * TN_ + t * 256 + nBase + nn) * 8 + wsel];
    }

    const int a_row = tid >> 3, a_kq = (tid & 7) * 16;

    float acc[4][4];
#pragma unroll
    for (int r = 0; r < 4; ++r)
#pragma unroll
        for (int t = 0; t < 4; ++t) acc[r][t] = 0.0f;

    for (int half = 0; half < 2; ++half) {
        if (half) __syncthreads();
#pragma unroll
        for (int j = 0; j < 4; ++j) {
            const float4 v = *(const float4*)&w[(size_t)(oBase + a_row) * C_ + half * 128 + a_kq + 4 * j];
            At[a_kq + 4 * j][a_row] = v.x;
            At[a_kq + 4 * j + 1][a_row] = v.y;
            At[a_kq + 4 * j + 2][a_row] = v.z;
            At[a_kq + 4 * j + 3][a_row] = v.w;
        }
        __syncthreads();

        for (int ks = 0; ks < 4; ++ks) {
            uint32_t wr[4];
#pragma unroll
            for (int t = 0; t < 4; ++t)
                wr[t] = Sw[(t * 32 + tx) * 9 + half * 4 + ks];
#pragma unroll
            for (int u = 0; u < 32; ++u) {
                float a[4];
                *(float4*)&a[0] = *(const float4*)&At[ks * 32 + u][ty * 4];
                float bv[4];
#pragma unroll
                for (int t = 0; t < 4; ++t) bv[t] = (float)((wr[t] >> u) & 1u);
#pragma unroll
                for (int r = 0; r < 4; ++r)
#pragma unroll
                    for (int t = 0; t < 4; ++t) acc[r][t] += a[r] * bv[t];
            }
        }
    }

#pragma unroll
    for (int r = 0; r < 4; ++r) {
        const int o = oBase + ty * 4 + r;
        const float inv = 1.0f / sqrtf(var[o] + 1e-5f);
        const float g = gamma[o] * inv;
        const float mn = mean[o], bt = beta[o], bpo = bp[o];
        float memv = 0.0f, spk = 0.0f;
#pragma unroll
        for (int t = 0; t < 4; ++t) {
            const float val = ((acc[r][t] + bpo) - mn) * g + bt;
            const float m = (memv - 0.5f * spk) * 0.25f + val;
            memv = m;
            const float s = quant1f(m);
            spk = s;
            out[(((size_t)t * B_ + b) * C_ + o) * N_ + nBase + tx] = s;
        }
    }
}

// ---------------------------------------------------------------------------
extern "C" void kernel_launch(void* const* d_in, const int* in_sizes, int n_in,
                              void* d_out, int out_size, void* d_ws, size_t ws_size,
                              hipStream_t stream)
{
    const float* x          = (const float*)d_in[0];
    const float* w_qkv      = (const float*)d_in[1];
    const float* qkv_gamma  = (const float*)d_in[2];
    const float* qkv_beta   = (const float*)d_in[3];
    const float* qkv_mean   = (const float*)d_in[4];
    const float* qkv_var    = (const float*)d_in[5];
    const float* bias_table = (const float*)d_in[6];
    const float* w_proj     = (const float*)d_in[7];
    const float* b_proj     = (const float*)d_in[8];
    const float* proj_gamma = (const float*)d_in[9];
    const float* proj_beta  = (const float*)d_in[10];
    const float* proj_mean  = (const float*)d_in[11];
    const float* proj_var   = (const float*)d_in[12];
    float* out = (float*)d_out;

    // workspace layout (bytes). parts live inside the dead qkv_bn region
    // (written only after K2 consumed it). Gf and Pt in the dead oatt region
    // (25165824+), overlap-free (R8's aliasing lesson).
    char* ws = (char*)d_ws;
    float*    qkv_bn = (float*)(ws + 0);            // 25165824 B (dead after K2)
    float*    part0  = (float*)(ws + 1048576);      //  8388608 B (after K2)
    float*    part1  = (float*)(ws + 9437184);      //  6291456 B
    float*    part2  = (float*)(ws + 15728640);     //  4194304 B
    float*    part3  = (float*)(ws + 19922944);     //  2097152 B (end 22020096)
    float*    Gf     = (float*)(ws + 25165824);     //  1048576 B (end 26214400)
    int*      Pt     = (int*)  (ws + 26214400);     //  1048576 B (end 27262976)
    uint32_t* s2c    = (uint32_t*)(ws + 33554432);  //   262144 B (packed spikes)
    uint32_t* qbits  = (uint32_t*)(ws + 50331648);  //   262144 B
    uint32_t* kbits  = (uint32_t*)(ws + 50593792);
    uint32_t* vbits  = (uint32_t*)(ws + 50855936);  // end 51118080

    k1_qkv_gemm<<<dim3(64, 6), 256, 0, stream>>>(
        x, w_qkv, qkv_gamma, qkv_beta, qkv_mean, qkv_var, qkv_bn);

    k2_lif_pack<<<dim3(24, 8, 4), 256, 0, stream>>>(qkv_bn, qbits, kbits, vbits);

    k3_tgp<<<dim3(4, 64), 256, 0, stream>>>(kbits, vbits, Pt);

    k3_cum<<<dim3(64), 256, 0, stream>>>(Pt, Gf);

    k3_bias_gemm<<<dim3(2, 2, 80), 256, 0, stream>>>(
        vbits, bias_table, part0, part1, part2, part3);

    k4_lif2<<<dim3(256, 8), 256, 0, stream>>>(
        qbits, Gf, part0, part1, part2, part3, s2c);

    k5_proj_lif<<<dim3(8, 8, 8), 256, 0, stream>>>(
        s2c, w_proj, b_proj, proj_gamma, proj_beta, proj_mean, proj_var, out);
}

// Round 13
// 216.165 us; speedup vs baseline: 1.0610x; 1.0610x over previous
//
#include <hip/hip_runtime.h>
#include <stdint.h>
#include <math.h>

// Problem constants
constexpr int T_ = 4;
constexpr int B_ = 8;
constexpr int C_ = 256;
constexpr int N_ = 256;          // H*W
constexpr int TN_ = 1024;        // T*N
constexpr int NH_ = 8;           // heads
constexpr int O3_ = 768;         // 3*C
constexpr int BIAS_ROWS_ = 6727; // 7*31*31

__device__ __constant__ int TI_OF[10] = {0,1,1,2,2,2,3,3,3,3};
__device__ __constant__ int TJ_OF[10] = {0,0,1,0,1,2,0,1,2,3};

__device__ __forceinline__ float quant1f(float m) {
    return rintf(fminf(fmaxf(m, 0.0f), 1.0f));
}

// ---------------------------------------------------------------------------
// K1: qkv = BN(w_qkv @ xf)   out[b][o][l]
// R11 config (best measured: 50.2us): 64x128 tile, 8x4 microtile, K-chunk 32,
// grid 8x12x8 = 768 blocks = 3/CU. R12's 128x128/8x8 regressed (1.5 blk/CU ->
// 1-2 waves/SIMD, VALUBusy 32%). Ascending-k accumulation.
// ---------------------------------------------------------------------------
__global__ __launch_bounds__(256) void k1_qkv_gemm(
    const float* __restrict__ x, const float* __restrict__ w,
    const float* __restrict__ gamma, const float* __restrict__ beta,
    const float* __restrict__ mean, const float* __restrict__ var,
    float* __restrict__ out)
{
    __shared__ float At[32][68];   // [k][m], m=64 (+4 pad)
    __shared__ float Bt[32][132];  // [k][n], n=128 (+4 pad)
    const int b = blockIdx.z;
    const int oBase = blockIdx.y * 64;
    const int lBase = blockIdx.x * 128;
    const int tid = threadIdx.x;
    const int tx = tid & 31;        // n: cols tx*4..+3
    const int ty = tid >> 5;        // m: rows {0,32}+ty*4..+3
    const float* xb = x + (size_t)b * C_ * TN_;

    float acc[8][4];
#pragma unroll
    for (int i = 0; i < 8; ++i)
#pragma unroll
        for (int j = 0; j < 4; ++j) acc[i][j] = 0.0f;

    const int a_row0 = tid >> 4, a_k2 = (tid & 15) * 2;
    const int b_kk0 = tid >> 5, b_c4 = (tid & 31) * 4;

    for (int kc = 0; kc < 8; ++kc) {
        const int k0 = kc * 32;
#pragma unroll
        for (int r = 0; r < 4; ++r) {
            const int row = a_row0 + 16 * r;
            const float2 v = *(const float2*)&w[(size_t)(oBase + row) * C_ + k0 + a_k2];
            At[a_k2][row] = v.x;
            At[a_k2 + 1][row] = v.y;
        }
#pragma unroll
        for (int r = 0; r < 4; ++r) {
            const int kk = b_kk0 + 8 * r;
            const float4 v = *(const float4*)&xb[(size_t)(k0 + kk) * TN_ + lBase + b_c4];
            *(float4*)&Bt[kk][b_c4] = v;
        }
        __syncthreads();
#pragma unroll
        for (int cc = 0; cc < 32; ++cc) {
            float a[8], bb[4];
            *(float4*)&a[0] = *(const float4*)&At[cc][ty * 4];
            *(float4*)&a[4] = *(const float4*)&At[cc][32 + ty * 4];
            *(float4*)&bb[0] = *(const float4*)&Bt[cc][tx * 4];
#pragma unroll
            for (int i = 0; i < 8; ++i)
#pragma unroll
                for (int j = 0; j < 4; ++j) acc[i][j] += a[i] * bb[j];
        }
        __syncthreads();
    }

#pragma unroll
    for (int i = 0; i < 8; ++i) {
        const int o = oBase + (i >> 2) * 32 + ty * 4 + (i & 3);
        const float inv = 1.0f / sqrtf(var[o] + 1e-5f);
        const float g = gamma[o] * inv;
        const float mn = mean[o], bt = beta[o];
        float4 st;
        st.x = (acc[i][0] - mn) * g + bt;
        st.y = (acc[i][1] - mn) * g + bt;
        st.z = (acc[i][2] - mn) * g + bt;
        st.w = (acc[i][3] - mn) * g + bt;
        *(float4*)&out[((size_t)b * O3_ + o) * TN_ + lBase + tx * 4] = st;
    }
}

// ---------------------------------------------------------------------------
// K2: LIF over t, pack spikes. d-quarter split (R12 config -- part of the
// ~32us "rest" win), uint8 stores. 768 blocks.
// ---------------------------------------------------------------------------
__global__ __launch_bounds__(256) void k2_lif_pack(
    const float* __restrict__ qkv,
    uint32_t* __restrict__ qb, uint32_t* __restrict__ kb, uint32_t* __restrict__ vb)
{
    const int n = threadIdx.x;
    const int g = blockIdx.x;
    const int b = blockIdx.y;
    const int dq = blockIdx.z;          // d = dq*8 .. dq*8+7
    const int which = g >> 3, h = g & 7;
    uint32_t* dstw = (which == 0) ? qb : (which == 1) ? kb : vb;
    uint8_t* dst = (uint8_t*)dstw;
    const float* src = qkv + ((size_t)b * O3_ + g * 32 + dq * 8) * TN_;

    float memv[8];
#pragma unroll
    for (int d = 0; d < 8; ++d) memv[d] = 0.0f;
    uint32_t prev = 0;

    for (int t = 0; t < T_; ++t) {
        uint32_t bits = 0;
#pragma unroll
        for (int d = 0; d < 8; ++d) {
            const float xv = src[(size_t)d * TN_ + t * N_ + n];
            const float m = (memv[d] - 0.5f * (float)((prev >> d) & 1u)) * 0.25f + xv;
            memv[d] = m;
            const float s = quant1f(m);
            bits |= ((uint32_t)s) << d;
        }
        prev = bits;
        dst[4 * (((size_t)b * NH_ + h) * TN_ + t * N_ + n) + dq] = (uint8_t)bits;
    }
}

// ---------------------------------------------------------------------------
// K3tgp: per-(t,bh) ballot bit-transpose + partial Gram (int). 256 blocks.
// ---------------------------------------------------------------------------
__global__ __launch_bounds__(256) void k3_tgp(
    const uint32_t* __restrict__ kb, const uint32_t* __restrict__ vb,
    int* __restrict__ Pt)
{
    __shared__ uint64_t ks[32][4];
    __shared__ uint64_t vs[32][4];
    const int t = blockIdx.x;
    const int bh = blockIdx.y;
    const int tid = threadIdx.x;
    const int q = tid >> 6, lane = tid & 63;
    const int j = t * N_ + q * 64 + lane;

    const uint32_t kw = kb[(size_t)bh * TN_ + j];
    const uint32_t vw = vb[(size_t)bh * TN_ + j];
#pragma unroll
    for (int d = 0; d < 32; ++d) {
        const uint64_t mk = __ballot((kw >> d) & 1u);
        const uint64_t mv = __ballot((vw >> d) & 1u);
        if (lane == 0) { ks[d][q] = mk; vs[d][q] = mv; }
    }
    __syncthreads();

    const int d = tid & 31;
#pragma unroll
    for (int s = 0; s < 4; ++s) {
        const int d2 = (tid >> 5) + 8 * s;
        int p = 0;
#pragma unroll
        for (int w = 0; w < 4; ++w) p += __popcll(ks[d2][w] & vs[d][w]);
        Pt[(size_t)(bh * 4 + t) * 1024 + d2 * 32 + d] = p;
    }
}

// ---------------------------------------------------------------------------
// K3cum: cumulative sum of partial Grams over t -> Gf (float).
// ---------------------------------------------------------------------------
__global__ __launch_bounds__(256) void k3_cum(
    const int* __restrict__ Pt, float* __restrict__ Gf)
{
    const int bh = blockIdx.x;
    const int tid = threadIdx.x;
#pragma unroll
    for (int r = 0; r < 4; ++r) {
        const int idx = tid + 256 * r;
        int cum = 0;
#pragma unroll
        for (int t = 0; t < T_; ++t) {
            cum += Pt[(size_t)(bh * 4 + t) * 1024 + idx];
            Gf[(size_t)(bh * 4 + t) * 1024 + idx] = (float)cum;
        }
    }
}

// ---------------------------------------------------------------------------
// K3gemm: balanced split-K bias GEMM -- R11 config (best measured: 50.2us):
// 64(i) x 128(n) tile, 4x8 microtile with 16B-stride compute reads, K-chunk
// 32, grid (2,4,80) = 640 blocks = 2.5/CU. Ascending-j order.
// ---------------------------------------------------------------------------
__global__ __launch_bounds__(256) void k3_bias_gemm(
    const uint32_t* __restrict__ vb, const float* __restrict__ bias_table,
    float* __restrict__ p0, float* __restrict__ p1,
    float* __restrict__ p2, float* __restrict__ p3)
{
    __shared__ float sbl[640];
    __shared__ float At[32][68];   // [j-in-chunk][i-local]
    __shared__ float Bt[32][132];  // [j-in-chunk][n-local]

    const int z = blockIdx.z;
    const int h = z / 10;
    const int p = z % 10;
    const int ti = TI_OF[p], tj = TJ_OF[p];
    const int dt = ti - tj;
    const int iT = blockIdx.y;
    const int nBase = blockIdx.x * 128;
    const int tid = threadIdx.x;

    const int base = 3363 + 961 * dt + 124 * iT - 480;
    for (int s = tid; s < 640; s += 256) {
        const int gidx = base + s;
        sbl[s] = (gidx < BIAS_ROWS_) ? bias_table[(size_t)gidx * NH_ + h] : 0.0f;
    }

    const int ty = tid >> 4, tx = tid & 15;

    // A-staging: cc = tx + 16r (r=0,1), rows iBase4..+3
    const int iBase4 = ty * 4;
    const int sIdxBase = 31 * (iBase4 >> 4) + (iBase4 & 15) + 480 - tx;

    // B-staging: rows kk = ty + 16r, cols tx*8..+7
    const int n8 = tx * 8;
    const int nS = nBase + n8;
    const int bS = nS >> 5, d0S = nS & 31;
    const uint32_t* vbw = vb + ((size_t)bS * NH_ + h) * TN_ + tj * 256 + ty;

    // Compute-column mapping (16B-stride reads): groups at tx*4 and 64+tx*4
    const int nA = nBase + tx * 4;
    const int nB = nBase + 64 + tx * 4;
    const int bA = nA >> 5, dA = nA & 31;
    const int bB = nB >> 5, dB = nB & 31;

    float acc[4][8];
#pragma unroll
    for (int i = 0; i < 4; ++i)
#pragma unroll
        for (int j = 0; j < 8; ++j) acc[i][j] = 0.0f;

    __syncthreads();  // sbl ready

    for (int kc = 0; kc < 8; ++kc) {
#pragma unroll
        for (int r = 0; r < 2; ++r) {
            const int s0 = sIdxBase - 31 * (kc * 2 + r);
            float4 av;
            av.x = sbl[s0];
            av.y = sbl[s0 + 1];
            av.z = sbl[s0 + 2];
            av.w = sbl[s0 + 3];
            *(float4*)&At[tx + 16 * r][iBase4] = av;
        }
#pragma unroll
        for (int r = 0; r < 2; ++r) {
            const uint32_t wd = vbw[kc * 32 + 16 * r];
            float4 b0, b1;
            b0.x = (float)((wd >> d0S) & 1u);
            b0.y = (float)((wd >> (d0S + 1)) & 1u);
            b0.z = (float)((wd >> (d0S + 2)) & 1u);
            b0.w = (float)((wd >> (d0S + 3)) & 1u);
            b1.x = (float)((wd >> (d0S + 4)) & 1u);
            b1.y = (float)((wd >> (d0S + 5)) & 1u);
            b1.z = (float)((wd >> (d0S + 6)) & 1u);
            b1.w = (float)((wd >> (d0S + 7)) & 1u);
            *(float4*)&Bt[ty + 16 * r][n8] = b0;
            *(float4*)&Bt[ty + 16 * r][n8 + 4] = b1;
        }
        __syncthreads();
#pragma unroll
        for (int cc = 0; cc < 32; ++cc) {
            float a[4], bb[8];
            *(float4*)&a[0] = *(const float4*)&At[cc][ty * 4];
            *(float4*)&bb[0] = *(const float4*)&Bt[cc][tx * 4];        // 16B stride
            *(float4*)&bb[4] = *(const float4*)&Bt[cc][64 + tx * 4];   // 16B stride
#pragma unroll
            for (int i = 0; i < 4; ++i)
#pragma unroll
                for (int j = 0; j < 8; ++j) acc[i][j] += a[i] * bb[j];
        }
        __syncthreads();
    }

    float* plane = (tj == 0) ? p0 : (tj == 1) ? p1 : (tj == 2) ? p2 : p3;
    const int nrows = (4 - tj) * 256;
    const int cA = h * 32 + dA;
    const int cB = h * 32 + dB;
#pragma unroll
    for (int r = 0; r < 4; ++r) {
        const int rowL = dt * 256 + iT * 64 + ty * 4 + r;
        float4 s0, s1;
        s0.x = acc[r][0]; s0.y = acc[r][1]; s0.z = acc[r][2]; s0.w = acc[r][3];
        s1.x = acc[r][4]; s1.y = acc[r][5]; s1.z = acc[r][6]; s1.w = acc[r][7];
        *(float4*)&plane[((size_t)bA * nrows + rowL) * 256 + cA] = s0;
        *(float4*)&plane[((size_t)bB * nrows + rowL) * 256 + cB] = s1;
    }
}

// ---------------------------------------------------------------------------
// K4: fused S1 + bias partials + LIF2 -> bit-packed spikes.
// ---------------------------------------------------------------------------
__global__ __launch_bounds__(256) void k4_lif2(
    const uint32_t* __restrict__ qb, const float* __restrict__ Gf,
    const float* __restrict__ p0, const float* __restrict__ p1,
    const float* __restrict__ p2, const float* __restrict__ p3,
    uint32_t* __restrict__ s2c)
{
    const int c = threadIdx.x;
    const int n = blockIdx.x;
    const int b = blockIdx.y;
    const int lane = c & 63;
    const int h = c >> 5, d = c & 31;
    const int bh = b * NH_ + h;
    const uint32_t* qbh = qb + (size_t)bh * TN_;

    float memv = 0.0f, spk = 0.0f;
    for (int t = 0; t < T_; ++t) {
        const int l = t * N_ + n;
        const uint32_t q = qbh[l];
        const float* g = Gf + (size_t)(bh * 4 + t) * 1024 + d;
        float v = 0.0f;
#pragma unroll
        for (int d2 = 0; d2 < 32; ++d2)
            v += ((q >> d2) & 1u) ? g[d2 * 32] : 0.0f;
        v += p0[((size_t)b * 1024 + l) * 256 + c];
        if (t >= 1) v += p1[((size_t)b * 768 + (l - 256)) * 256 + c];
        if (t >= 2) v += p2[((size_t)b * 512 + (l - 512)) * 256 + c];
        if (t >= 3) v += p3[((size_t)b * 256 + (l - 768)) * 256 + c];
        const float m = (memv - 0.5f * spk) * 0.25f + 0.125f * v;
        memv = m;
        const float s = quant1f(m);
        spk = s;
        const uint64_t mask = __ballot(s != 0.0f);
        if (lane == 0)
            s2c[((size_t)b * TN_ + l) * 8 + (c >> 5)] = (uint32_t)mask;
        else if (lane == 32)
            s2c[((size_t)b * TN_ + l) * 8 + (c >> 5)] = (uint32_t)(mask >> 32);
    }
}

// ---------------------------------------------------------------------------
// K5: fused proj GEMM + bias + BN + final LIF -> writes d_out directly.
// ---------------------------------------------------------------------------
__global__ __launch_bounds__(256) void k5_proj_lif(
    const uint32_t* __restrict__ s2c, const float* __restrict__ w,
    const float* __restrict__ bp,
    const float* __restrict__ gamma, const float* __restrict__ beta,
    const float* __restrict__ mean, const float* __restrict__ var,
    float* __restrict__ out)
{
    __shared__ float At[128][36];    // [k-local][row], 32 rows (+4 pad)
    __shared__ uint32_t Sw[128 * 9]; // [l'][8 words] padded to 9
    const int nBase = blockIdx.x * 32;
    const int oBase = blockIdx.y * 32;
    const int b = blockIdx.z;
    const int tid = threadIdx.x;
    const int tx = tid & 31;   // n = nBase + tx
    const int ty = tid >> 5;   // rows ty*4..+3

#pragma unroll
    for (int j = 0; j < 4; ++j) {
        const int fidx = tid * 4 + j;
        const int lp = fidx >> 3, wsel = fidx & 7;
        const int t = lp >> 5, nn = lp & 31;
        Sw[lp * 9 + wsel] = s2c[((size_t)b * TN_ + t * 256 + nBase + nn) * 8 + wsel];
    }

    const int a_row = tid >> 3, a_kq = (tid & 7) * 16;

    float acc[4][4];
#pragma unroll
    for (int r = 0; r < 4; ++r)
#pragma unroll
        for (int t = 0; t < 4; ++t) acc[r][t] = 0.0f;

    for (int half = 0; half < 2; ++half) {
        if (half) __syncthreads();
#pragma unroll
        for (int j = 0; j < 4; ++j) {
            const float4 v = *(const float4*)&w[(size_t)(oBase + a_row) * C_ + half * 128 + a_kq + 4 * j];
            At[a_kq + 4 * j][a_row] = v.x;
            At[a_kq + 4 * j + 1][a_row] = v.y;
            At[a_kq + 4 * j + 2][a_row] = v.z;
            At[a_kq + 4 * j + 3][a_row] = v.w;
        }
        __syncthreads();

        for (int ks = 0; ks < 4; ++ks) {
            uint32_t wr[4];
#pragma unroll
            for (int t = 0; t < 4; ++t)
                wr[t] = Sw[(t * 32 + tx) * 9 + half * 4 + ks];
#pragma unroll
            for (int u = 0; u < 32; ++u) {
                float a[4];
                *(float4*)&a[0] = *(const float4*)&At[ks * 32 + u][ty * 4];
                float bv[4];
#pragma unroll
                for (int t = 0; t < 4; ++t) bv[t] = (float)((wr[t] >> u) & 1u);
#pragma unroll
                for (int r = 0; r < 4; ++r)
#pragma unroll
                    for (int t = 0; t < 4; ++t) acc[r][t] += a[r] * bv[t];
            }
        }
    }

#pragma unroll
    for (int r = 0; r < 4; ++r) {
        const int o = oBase + ty * 4 + r;
        const float inv = 1.0f / sqrtf(var[o] + 1e-5f);
        const float g = gamma[o] * inv;
        const float mn = mean[o], bt = beta[o], bpo = bp[o];
        float memv = 0.0f, spk = 0.0f;
#pragma unroll
        for (int t = 0; t < 4; ++t) {
            const float val = ((acc[r][t] + bpo) - mn) * g + bt;
            const float m = (memv - 0.5f * spk) * 0.25f + val;
            memv = m;
            const float s = quant1f(m);
            spk = s;
            out[(((size_t)t * B_ + b) * C_ + o) * N_ + nBase + tx] = s;
        }
    }
}

// ---------------------------------------------------------------------------
extern "C" void kernel_launch(void* const* d_in, const int* in_sizes, int n_in,
                              void* d_out, int out_size, void* d_ws, size_t ws_size,
                              hipStream_t stream)
{
    const float* x          = (const float*)d_in[0];
    const float* w_qkv      = (const float*)d_in[1];
    const float* qkv_gamma  = (const float*)d_in[2];
    const float* qkv_beta   = (const float*)d_in[3];
    const float* qkv_mean   = (const float*)d_in[4];
    const float* qkv_var    = (const float*)d_in[5];
    const float* bias_table = (const float*)d_in[6];
    const float* w_proj     = (const float*)d_in[7];
    const float* b_proj     = (const float*)d_in[8];
    const float* proj_gamma = (const float*)d_in[9];
    const float* proj_beta  = (const float*)d_in[10];
    const float* proj_mean  = (const float*)d_in[11];
    const float* proj_var   = (const float*)d_in[12];
    float* out = (float*)d_out;

    // workspace layout (bytes). parts inside the dead qkv_bn region (written
    // only after K2 consumed it); Gf/Pt in the dead oatt region (R8 lesson).
    char* ws = (char*)d_ws;
    float*    qkv_bn = (float*)(ws + 0);            // 25165824 B (dead after K2)
    float*    part0  = (float*)(ws + 1048576);      //  8388608 B (after K2)
    float*    part1  = (float*)(ws + 9437184);      //  6291456 B
    float*    part2  = (float*)(ws + 15728640);     //  4194304 B
    float*    part3  = (float*)(ws + 19922944);     //  2097152 B (end 22020096)
    float*    Gf     = (float*)(ws + 25165824);     //  1048576 B (end 26214400)
    int*      Pt     = (int*)  (ws + 26214400);     //  1048576 B (end 27262976)
    uint32_t* s2c    = (uint32_t*)(ws + 33554432);  //   262144 B (packed spikes)
    uint32_t* qbits  = (uint32_t*)(ws + 50331648);  //   262144 B
    uint32_t* kbits  = (uint32_t*)(ws + 50593792);
    uint32_t* vbits  = (uint32_t*)(ws + 50855936);  // end 51118080

    k1_qkv_gemm<<<dim3(8, 12, 8), 256, 0, stream>>>(
        x, w_qkv, qkv_gamma, qkv_beta, qkv_mean, qkv_var, qkv_bn);

    k2_lif_pack<<<dim3(24, 8, 4), 256, 0, stream>>>(qkv_bn, qbits, kbits, vbits);

    k3_tgp<<<dim3(4, 64), 256, 0, stream>>>(kbits, vbits, Pt);

    k3_cum<<<dim3(64), 256, 0, stream>>>(Pt, Gf);

    k3_bias_gemm<<<dim3(2, 4, 80), 256, 0, stream>>>(
        vbits, bias_table, part0, part1, part2, part3);

    k4_lif2<<<dim3(256, 8), 256, 0, stream>>>(
        qbits, Gf, part0, part1, part2, part3, s2c);

    k5_proj_lif<<<dim3(8, 8, 8), 256, 0, stream>>>(
        s2c, w_proj, b_proj, proj_gamma, proj_beta, proj_mean, proj_var, out);
}

// Round 14
// 213.802 us; speedup vs baseline: 1.0727x; 1.0111x over previous
//
#include <hip/hip_runtime.h>
#include <stdint.h>
#include <math.h>

// Problem constants
constexpr int T_ = 4;
constexpr int B_ = 8;
constexpr int C_ = 256;
constexpr int N_ = 256;          // H*W
constexpr int TN_ = 1024;        // T*N
constexpr int NH_ = 8;           // heads
constexpr int O3_ = 768;         // 3*C
constexpr int BIAS_ROWS_ = 6727; // 7*31*31

__device__ __constant__ int TI_OF[10] = {0,1,1,2,2,2,3,3,3,3};
__device__ __constant__ int TJ_OF[10] = {0,0,1,0,1,2,0,1,2,3};

__device__ __forceinline__ float quant1f(float m) {
    return rintf(fminf(fmaxf(m, 0.0f), 1.0f));
}

// ---------------------------------------------------------------------------
// K1: qkv = BN(w_qkv @ xf)   out[b][o][l]
// 32(M) x 128(N) tile, 4x4 microtile, K-chunk 32. Grid 8x24x8 = 1536 blocks
// = 6/CU (LDS 25.6KB -> exactly 6 fit). R13 law: these GEMMs scale with
// blocks/CU (1.5->70us, 3->50us); grid was the binding limit, not LDS/VGPR.
// Full ascending-k accumulation per output element (bit-identical).
// ---------------------------------------------------------------------------
__global__ __launch_bounds__(256) void k1_qkv_gemm(
    const float* __restrict__ x, const float* __restrict__ w,
    const float* __restrict__ gamma, const float* __restrict__ beta,
    const float* __restrict__ mean, const float* __restrict__ var,
    float* __restrict__ out)
{
    __shared__ float At[32][36];   // [k][m], m=32 (+4 pad)
    __shared__ float Bt[32][132];  // [k][n], n=128 (+4 pad)
    const int b = blockIdx.z;
    const int oBase = blockIdx.y * 32;
    const int lBase = blockIdx.x * 128;
    const int tid = threadIdx.x;
    const int tx = tid & 31;        // n: cols tx*4..+3
    const int ty = tid >> 5;        // m: rows ty*4..+3 (8 groups x 4 = 32)
    const float* xb = x + (size_t)b * C_ * TN_;

    float acc[4][4];
#pragma unroll
    for (int i = 0; i < 4; ++i)
#pragma unroll
        for (int j = 0; j < 4; ++j) acc[i][j] = 0.0f;

    // A loader: 32 rows x 32 k = 1024 floats; 2 rows x float2 per thread
    const int a_row0 = tid >> 4, a_k2 = (tid & 15) * 2;
    // B loader: 32 k x 128 cols = 4096 floats; 4 float4 per thread
    const int b_kk0 = tid >> 5, b_c4 = (tid & 31) * 4;

    for (int kc = 0; kc < 8; ++kc) {
        const int k0 = kc * 32;
#pragma unroll
        for (int r = 0; r < 2; ++r) {
            const int row = a_row0 + 16 * r;
            const float2 v = *(const float2*)&w[(size_t)(oBase + row) * C_ + k0 + a_k2];
            At[a_k2][row] = v.x;
            At[a_k2 + 1][row] = v.y;
        }
#pragma unroll
        for (int r = 0; r < 4; ++r) {
            const int kk = b_kk0 + 8 * r;
            const float4 v = *(const float4*)&xb[(size_t)(k0 + kk) * TN_ + lBase + b_c4];
            *(float4*)&Bt[kk][b_c4] = v;
        }
        __syncthreads();
#pragma unroll
        for (int cc = 0; cc < 32; ++cc) {
            float a[4], bb[4];
            *(float4*)&a[0] = *(const float4*)&At[cc][ty * 4];
            *(float4*)&bb[0] = *(const float4*)&Bt[cc][tx * 4];
#pragma unroll
            for (int i = 0; i < 4; ++i)
#pragma unroll
                for (int j = 0; j < 4; ++j) acc[i][j] += a[i] * bb[j];
        }
        __syncthreads();
    }

#pragma unroll
    for (int i = 0; i < 4; ++i) {
        const int o = oBase + ty * 4 + i;
        const float inv = 1.0f / sqrtf(var[o] + 1e-5f);
        const float g = gamma[o] * inv;
        const float mn = mean[o], bt = beta[o];
        float4 st;
        st.x = (acc[i][0] - mn) * g + bt;
        st.y = (acc[i][1] - mn) * g + bt;
        st.z = (acc[i][2] - mn) * g + bt;
        st.w = (acc[i][3] - mn) * g + bt;
        *(float4*)&out[((size_t)b * O3_ + o) * TN_ + lBase + tx * 4] = st;
    }
}

// ---------------------------------------------------------------------------
// K2: LIF over t, pack spikes. d-quarter split, uint8 stores. 768 blocks.
// ---------------------------------------------------------------------------
__global__ __launch_bounds__(256) void k2_lif_pack(
    const float* __restrict__ qkv,
    uint32_t* __restrict__ qb, uint32_t* __restrict__ kb, uint32_t* __restrict__ vb)
{
    const int n = threadIdx.x;
    const int g = blockIdx.x;
    const int b = blockIdx.y;
    const int dq = blockIdx.z;          // d = dq*8 .. dq*8+7
    const int which = g >> 3, h = g & 7;
    uint32_t* dstw = (which == 0) ? qb : (which == 1) ? kb : vb;
    uint8_t* dst = (uint8_t*)dstw;
    const float* src = qkv + ((size_t)b * O3_ + g * 32 + dq * 8) * TN_;

    float memv[8];
#pragma unroll
    for (int d = 0; d < 8; ++d) memv[d] = 0.0f;
    uint32_t prev = 0;

    for (int t = 0; t < T_; ++t) {
        uint32_t bits = 0;
#pragma unroll
        for (int d = 0; d < 8; ++d) {
            const float xv = src[(size_t)d * TN_ + t * N_ + n];
            const float m = (memv[d] - 0.5f * (float)((prev >> d) & 1u)) * 0.25f + xv;
            memv[d] = m;
            const float s = quant1f(m);
            bits |= ((uint32_t)s) << d;
        }
        prev = bits;
        dst[4 * (((size_t)b * NH_ + h) * TN_ + t * N_ + n) + dq] = (uint8_t)bits;
    }
}

// ---------------------------------------------------------------------------
// K3tgp: per-(t,bh) ballot bit-transpose + partial Gram (int). 256 blocks.
// ---------------------------------------------------------------------------
__global__ __launch_bounds__(256) void k3_tgp(
    const uint32_t* __restrict__ kb, const uint32_t* __restrict__ vb,
    int* __restrict__ Pt)
{
    __shared__ uint64_t ks[32][4];
    __shared__ uint64_t vs[32][4];
    const int t = blockIdx.x;
    const int bh = blockIdx.y;
    const int tid = threadIdx.x;
    const int q = tid >> 6, lane = tid & 63;
    const int j = t * N_ + q * 64 + lane;

    const uint32_t kw = kb[(size_t)bh * TN_ + j];
    const uint32_t vw = vb[(size_t)bh * TN_ + j];
#pragma unroll
    for (int d = 0; d < 32; ++d) {
        const uint64_t mk = __ballot((kw >> d) & 1u);
        const uint64_t mv = __ballot((vw >> d) & 1u);
        if (lane == 0) { ks[d][q] = mk; vs[d][q] = mv; }
    }
    __syncthreads();

    const int d = tid & 31;
#pragma unroll
    for (int s = 0; s < 4; ++s) {
        const int d2 = (tid >> 5) + 8 * s;
        int p = 0;
#pragma unroll
        for (int w = 0; w < 4; ++w) p += __popcll(ks[d2][w] & vs[d][w]);
        Pt[(size_t)(bh * 4 + t) * 1024 + d2 * 32 + d] = p;
    }
}

// ---------------------------------------------------------------------------
// K3cum: cumulative sum of partial Grams over t -> Gf (float).
// ---------------------------------------------------------------------------
__global__ __launch_bounds__(256) void k3_cum(
    const int* __restrict__ Pt, float* __restrict__ Gf)
{
    const int bh = blockIdx.x;
    const int tid = threadIdx.x;
#pragma unroll
    for (int r = 0; r < 4; ++r) {
        const int idx = tid + 256 * r;
        int cum = 0;
#pragma unroll
        for (int t = 0; t < T_; ++t) {
            cum += Pt[(size_t)(bh * 4 + t) * 1024 + idx];
            Gf[(size_t)(bh * 4 + t) * 1024 + idx] = (float)cum;
        }
    }
}

// ---------------------------------------------------------------------------
// K3gemm: balanced split-K bias GEMM. 32(i) x 128(n) tile, 4x4 microtile,
// K-chunk 32, grid (2,8,80) = 1280 blocks = 5/CU. Ascending-j order
// (bit-identical). Bias window 544 floats (derivation: local idx = 480 +
// 31*(il>>4) + (il&15) - 31*(2kc+r1) - tx  in [0,527)).
// ---------------------------------------------------------------------------
__global__ __launch_bounds__(256) void k3_bias_gemm(
    const uint32_t* __restrict__ vb, const float* __restrict__ bias_table,
    float* __restrict__ p0, float* __restrict__ p1,
    float* __restrict__ p2, float* __restrict__ p3)
{
    __shared__ float sbl[544];
    __shared__ float At[32][36];   // [j-in-chunk][i-local 0..31]
    __shared__ float Bt[32][132];  // [j-in-chunk][n-local 0..127]

    const int z = blockIdx.z;
    const int h = z / 10;
    const int p = z % 10;
    const int ti = TI_OF[p], tj = TJ_OF[p];
    const int dt = ti - tj;
    const int iT = blockIdx.y;           // 0..7 (32 rows each)
    const int nBase = blockIdx.x * 128;  // 0 or 128
    const int tid = threadIdx.x;

    // stage bias window
    const int base = 3363 + 961 * dt + 62 * iT - 480;
    for (int s = tid; s < 544; s += 256) {
        const int gidx = base + s;
        sbl[s] = (gidx >= 0 && gidx < BIAS_ROWS_) ? bias_table[(size_t)gidx * NH_ + h] : 0.0f;
    }

    const int ty2 = tid >> 4, tx16 = tid & 15;   // staging mapping

    // A-staging: cc = tx16 + 16*r1, rows il = ty2*2, ty2*2+1 (il even ->
    // il,il+1 share the same h-block; window idx consecutive)
    const int il0 = ty2 * 2;
    const int sRowBase = 480 + 31 * (il0 >> 4) + (il0 & 15) - tx16;

    // B-staging: rows kk = ty2 + 16r, cols tx16*8..+7
    const int n8 = tx16 * 8;
    const int nS = nBase + n8;
    const int bS = nS >> 5, d0S = nS & 31;
    const uint32_t* vbw = vb + ((size_t)bS * NH_ + h) * TN_ + tj * 256 + ty2;

    // compute mapping: tyc rows (8 x 4 = 32), txc cols (32 x 4 = 128)
    const int tyc = tid >> 5, txc = tid & 31;
    const int nA = nBase + txc * 4;
    const int bA = nA >> 5, dA = nA & 31;

    float acc[4][4];
#pragma unroll
    for (int i = 0; i < 4; ++i)
#pragma unroll
        for (int j = 0; j < 4; ++j) acc[i][j] = 0.0f;

    __syncthreads();  // sbl ready

    for (int kc = 0; kc < 8; ++kc) {
#pragma unroll
        for (int r1 = 0; r1 < 2; ++r1) {
            const int s0 = sRowBase - 31 * (kc * 2 + r1);
            float2 av;
            av.x = sbl[s0];
            av.y = sbl[s0 + 1];
            At[tx16 + 16 * r1][il0] = av.x;
            At[tx16 + 16 * r1][il0 + 1] = av.y;
        }
#pragma unroll
        for (int r = 0; r < 2; ++r) {
            const uint32_t wd = vbw[kc * 32 + 16 * r];
            float4 b0, b1;
            b0.x = (float)((wd >> d0S) & 1u);
            b0.y = (float)((wd >> (d0S + 1)) & 1u);
            b0.z = (float)((wd >> (d0S + 2)) & 1u);
            b0.w = (float)((wd >> (d0S + 3)) & 1u);
            b1.x = (float)((wd >> (d0S + 4)) & 1u);
            b1.y = (float)((wd >> (d0S + 5)) & 1u);
            b1.z = (float)((wd >> (d0S + 6)) & 1u);
            b1.w = (float)((wd >> (d0S + 7)) & 1u);
            *(float4*)&Bt[ty2 + 16 * r][n8] = b0;
            *(float4*)&Bt[ty2 + 16 * r][n8 + 4] = b1;
        }
        __syncthreads();
#pragma unroll
        for (int cc = 0; cc < 32; ++cc) {
            float a[4], bb[4];
            *(float4*)&a[0] = *(const float4*)&At[cc][tyc * 4];
            *(float4*)&bb[0] = *(const float4*)&Bt[cc][txc * 4];  // 16B stride
#pragma unroll
            for (int i = 0; i < 4; ++i)
#pragma unroll
                for (int j = 0; j < 4; ++j) acc[i][j] += a[i] * bb[j];
        }
        __syncthreads();
    }

    float* plane = (tj == 0) ? p0 : (tj == 1) ? p1 : (tj == 2) ? p2 : p3;
    const int nrows = (4 - tj) * 256;
    const int cA = h * 32 + dA;
#pragma unroll
    for (int r = 0; r < 4; ++r) {
        const int rowL = dt * 256 + iT * 32 + tyc * 4 + r;
        float4 s0;
        s0.x = acc[r][0]; s0.y = acc[r][1]; s0.z = acc[r][2]; s0.w = acc[r][3];
        *(float4*)&plane[((size_t)bA * nrows + rowL) * 256 + cA] = s0;
    }
}

// ---------------------------------------------------------------------------
// K4: fused S1 + bias partials + LIF2 -> bit-packed spikes.
// ---------------------------------------------------------------------------
__global__ __launch_bounds__(256) void k4_lif2(
    const uint32_t* __restrict__ qb, const float* __restrict__ Gf,
    const float* __restrict__ p0, const float* __restrict__ p1,
    const float* __restrict__ p2, const float* __restrict__ p3,
    uint32_t* __restrict__ s2c)
{
    const int c = threadIdx.x;
    const int n = blockIdx.x;
    const int b = blockIdx.y;
    const int lane = c & 63;
    const int h = c >> 5, d = c & 31;
    const int bh = b * NH_ + h;
    const uint32_t* qbh = qb + (size_t)bh * TN_;

    float memv = 0.0f, spk = 0.0f;
    for (int t = 0; t < T_; ++t) {
        const int l = t * N_ + n;
        const uint32_t q = qbh[l];
        const float* g = Gf + (size_t)(bh * 4 + t) * 1024 + d;
        float v = 0.0f;
#pragma unroll
        for (int d2 = 0; d2 < 32; ++d2)
            v += ((q >> d2) & 1u) ? g[d2 * 32] : 0.0f;
        v += p0[((size_t)b * 1024 + l) * 256 + c];
        if (t >= 1) v += p1[((size_t)b * 768 + (l - 256)) * 256 + c];
        if (t >= 2) v += p2[((size_t)b * 512 + (l - 512)) * 256 + c];
        if (t >= 3) v += p3[((size_t)b * 256 + (l - 768)) * 256 + c];
        const float m = (memv - 0.5f * spk) * 0.25f + 0.125f * v;
        memv = m;
        const float s = quant1f(m);
        spk = s;
        const uint64_t mask = __ballot(s != 0.0f);
        if (lane == 0)
            s2c[((size_t)b * TN_ + l) * 8 + (c >> 5)] = (uint32_t)mask;
        else if (lane == 32)
            s2c[((size_t)b * TN_ + l) * 8 + (c >> 5)] = (uint32_t)(mask >> 32);
    }
}

// ---------------------------------------------------------------------------
// K5: fused proj GEMM + bias + BN + final LIF -> writes d_out directly.
// ---------------------------------------------------------------------------
__global__ __launch_bounds__(256) void k5_proj_lif(
    const uint32_t* __restrict__ s2c, const float* __restrict__ w,
    const float* __restrict__ bp,
    const float* __restrict__ gamma, const float* __restrict__ beta,
    const float* __restrict__ mean, const float* __restrict__ var,
    float* __restrict__ out)
{
    __shared__ float At[128][36];    // [k-local][row], 32 rows (+4 pad)
    __shared__ uint32_t Sw[128 * 9]; // [l'][8 words] padded to 9
    const int nBase = blockIdx.x * 32;
    const int oBase = blockIdx.y * 32;
    const int b = blockIdx.z;
    const int tid = threadIdx.x;
    const int tx = tid & 31;   // n = nBase + tx
    const int ty = tid >> 5;   // rows ty*4..+3

#pragma unroll
    for (int j = 0; j < 4; ++j) {
        const int fidx = tid * 4 + j;
        const int lp = fidx >> 3, wsel = fidx & 7;
        const int t = lp >> 5, nn = lp & 31;
        Sw[lp * 9 + wsel] = s2c[((size_t)b * TN_ + t * 256 + nBase + nn) * 8 + wsel];
    }

    const int a_row = tid >> 3, a_kq = (tid & 7) * 16;

    float acc[4][4];
#pragma unroll
    for (int r = 0; r < 4; ++r)
#pragma unroll
        for (int t = 0; t < 4; ++t) acc[r][t] = 0.0f;

    for (int half = 0; half < 2; ++half) {
        if (half) __syncthreads();
#pragma unroll
        for (int j = 0; j < 4; ++j) {
            const float4 v = *(const float4*)&w[(size_t)(oBase + a_row) * C_ + half * 128 + a_kq + 4 * j];
            At[a_kq + 4 * j][a_row] = v.x;
            At[a_kq + 4 * j + 1][a_row] = v.y;
            At[a_kq + 4 * j + 2][a_row] = v.z;
            At[a_kq + 4 * j + 3][a_row] = v.w;
        }
        __syncthreads();

        for (int ks = 0; ks < 4; ++ks) {
            uint32_t wr[4];
#pragma unroll
            for (int t = 0; t < 4; ++t)
                wr[t] = Sw[(t * 32 + tx) * 9 + half * 4 + ks];
#pragma unroll
            for (int u = 0; u < 32; ++u) {
                float a[4];
                *(float4*)&a[0] = *(const float4*)&At[ks * 32 + u][ty * 4];
                float bv[4];
#pragma unroll
                for (int t = 0; t < 4; ++t) bv[t] = (float)((wr[t] >> u) & 1u);
#pragma unroll
                for (int r = 0; r < 4; ++r)
#pragma unroll
                    for (int t = 0; t < 4; ++t) acc[r][t] += a[r] * bv[t];
            }
        }
    }

#pragma unroll
    for (int r = 0; r < 4; ++r) {
        const int o = oBase + ty * 4 + r;
        const float inv = 1.0f / sqrtf(var[o] + 1e-5f);
        const float g = gamma[o] * inv;
        const float mn = mean[o], bt = beta[o], bpo = bp[o];
        float memv = 0.0f, spk = 0.0f;
#pragma unroll
        for (int t = 0; t < 4; ++t) {
            const float val = ((acc[r][t] + bpo) - mn) * g + bt;
            const float m = (memv - 0.5f * spk) * 0.25f + val;
            memv = m;
            const float s = quant1f(m);
            spk = s;
            out[(((size_t)t * B_ + b) * C_ + o) * N_ + nBase + tx] = s;
        }
    }
}

// ---------------------------------------------------------------------------
extern "C" void kernel_launch(void* const* d_in, const int* in_sizes, int n_in,
                              void* d_out, int out_size, void* d_ws, size_t ws_size,
                              hipStream_t stream)
{
    const float* x          = (const float*)d_in[0];
    const float* w_qkv      = (const float*)d_in[1];
    const float* qkv_gamma  = (const float*)d_in[2];
    const float* qkv_beta   = (const float*)d_in[3];
    const float* qkv_mean   = (const float*)d_in[4];
    const float* qkv_var    = (const float*)d_in[5];
    const float* bias_table = (const float*)d_in[6];
    const float* w_proj     = (const float*)d_in[7];
    const float* b_proj     = (const float*)d_in[8];
    const float* proj_gamma = (const float*)d_in[9];
    const float* proj_beta  = (const float*)d_in[10];
    const float* proj_mean  = (const float*)d_in[11];
    const float* proj_var   = (const float*)d_in[12];
    float* out = (float*)d_out;

    // workspace layout (bytes). parts inside the dead qkv_bn region (written
    // only after K2 consumed it); Gf/Pt in the dead oatt region (R8 lesson).
    char* ws = (char*)d_ws;
    float*    qkv_bn = (float*)(ws + 0);            // 25165824 B (dead after K2)
    float*    part0  = (float*)(ws + 1048576);      //  8388608 B (after K2)
    float*    part1  = (float*)(ws + 9437184);      //  6291456 B
    float*    part2  = (float*)(ws + 15728640);     //  4194304 B
    float*    part3  = (float*)(ws + 19922944);     //  2097152 B (end 22020096)
    float*    Gf     = (float*)(ws + 25165824);     //  1048576 B (end 26214400)
    int*      Pt     = (int*)  (ws + 26214400);     //  1048576 B (end 27262976)
    uint32_t* s2c    = (uint32_t*)(ws + 33554432);  //   262144 B (packed spikes)
    uint32_t* qbits  = (uint32_t*)(ws + 50331648);  //   262144 B
    uint32_t* kbits  = (uint32_t*)(ws + 50593792);
    uint32_t* vbits  = (uint32_t*)(ws + 50855936);  // end 51118080

    k1_qkv_gemm<<<dim3(8, 24, 8), 256, 0, stream>>>(
        x, w_qkv, qkv_gamma, qkv_beta, qkv_mean, qkv_var, qkv_bn);

    k2_lif_pack<<<dim3(24, 8, 4), 256, 0, stream>>>(qkv_bn, qbits, kbits, vbits);

    k3_tgp<<<dim3(4, 64), 256, 0, stream>>>(kbits, vbits, Pt);

    k3_cum<<<dim3(64), 256, 0, stream>>>(Pt, Gf);

    k3_bias_gemm<<<dim3(2, 8, 80), 256, 0, stream>>>(
        vbits, bias_table, part0, part1, part2, part3);

    k4_lif2<<<dim3(256, 8), 256, 0, stream>>>(
        qbits, Gf, part0, part1, part2, part3, s2c);

    k5_proj_lif<<<dim3(8, 8, 8), 256, 0, stream>>>(
        s2c, w_proj, b_proj, proj_gamma, proj_beta, proj_mean, proj_var, out);
}